// Round 2
// baseline (795.898 us; speedup 1.0000x reference)
//
#include <hip/hip_runtime.h>
#include <hip/hip_cooperative_groups.h>
#include <math.h>

namespace cg = cooperative_groups;

// Problem constants (shapes fixed by the reference)
#define D 128
#define HH 128
#define CC 64
#define NLAYERS 3
#define LN_EPS 1e-5f

typedef __attribute__((ext_vector_type(8))) short bf16x8;
typedef __attribute__((ext_vector_type(4))) float f32x4;
typedef unsigned short u16;
typedef unsigned int u32;

// round-to-nearest-even fp32 -> bf16 bits
__device__ __forceinline__ u16 f2bf(float f) {
    u32 u = __float_as_uint(f);
    u32 r = u + 0x7FFFu + ((u >> 16) & 1u);
    return (u16)(r >> 16);
}
__device__ __forceinline__ float bf2f(u16 h) {
    return __uint_as_float(((u32)h) << 16);
}

// ---------------------------------------------------------------------------
// k_prep: fused setup — x->bf16 (float4-vectorized, into xcH cols 0:128) +
// tile Wg (3 layers) + tile W1 + tile W2 (hi/lo).
// Tiled layout: [kc][q][n][j], k = kc*32 + q*8 + j.
// (cnt zeroing lives in the cooperative CSR kernel.)
// ---------------------------------------------------------------------------
__global__ void k_prep(const float* __restrict__ x, u16* __restrict__ xh,
                       const float* __restrict__ Wg, u16* __restrict__ WgtH,
                       const float* __restrict__ W1, u16* __restrict__ W1tH,
                       const float* __restrict__ W2, u16* __restrict__ W2tH,
                       u16* __restrict__ W2tL, int N)
{
    int i = blockIdx.x * blockDim.x + threadIdx.x;
    // seg 0: x -> bf16 hi, 4 elements per thread (float4 load, ushort4 store)
    int nx4 = N * (D / 4);
    if (i < nx4) {
        float4 v = *(const float4*)(x + (size_t)i * 4);
        int row = i >> 5, c = (i & 31) << 2;
        ushort4 o;
        o.x = f2bf(v.x); o.y = f2bf(v.y); o.z = f2bf(v.z); o.w = f2bf(v.w);
        *(ushort4*)&xh[(size_t)row * 512 + c] = o;
        return;
    }
    i -= nx4;
    // seg 1: Wg (3 stacked 128x128 matrices; layout linear in kc)
    if (i < NLAYERS * D * HH) {
        int k = i >> 7, n = i & 127;
        int kc = k >> 5, q = (k >> 3) & 3, j = k & 7;
        WgtH[(((kc * 4 + q) << 7) + n) * 8 + j] = f2bf(Wg[i]);
        return;
    }
    i -= NLAYERS * D * HH;
    // seg 2: W1 (512x128)
    if (i < (D + NLAYERS * HH) * HH) {
        int k = i >> 7, n = i & 127;
        int kc = k >> 5, q = (k >> 3) & 3, j = k & 7;
        W1tH[(((kc * 4 + q) << 7) + n) * 8 + j] = f2bf(W1[i]);
        return;
    }
    i -= (D + NLAYERS * HH) * HH;
    // seg 3: W2 (128x64), hi + lo (split-3 in mlp phase 2)
    if (i < HH * CC) {
        int k = i >> 6, n = i & 63;
        int kc = k >> 5, q = (k >> 3) & 3, j = k & 7;
        float v = W2[i];
        u16 h = f2bf(v);
        int o = (((kc * 4 + q) << 6) + n) * 8 + j;
        W2tH[o] = h;
        W2tL[o] = f2bf(v - bf2f(h));
    }
}

// ---------------------------------------------------------------------------
// Cooperative CSR build: zero -> count -> chunk scan -> bsum scan -> apply
// (+dinv) -> scatter, all in one launch with grid syncs.
// Grid MUST be co-resident: 1024 blocks x 256 threads (4 waves/block).
// ---------------------------------------------------------------------------
__global__ __launch_bounds__(256) void k_csr(
    const int* __restrict__ src, const int* __restrict__ dst,
    int* __restrict__ cnt, int* __restrict__ rowptr, int* __restrict__ bsum,
    int* __restrict__ cursor, float* __restrict__ dinv,
    int2* __restrict__ ecol, int N, int E)
{
    cg::grid_group grid = cg::this_grid();
    __shared__ int s[256];
    __shared__ int carry;
    const int tid = threadIdx.x;
    const int gsz = gridDim.x * 256;
    const int gi  = blockIdx.x * 256 + tid;
    const int nch = (N + 255) >> 8;

    // A: zero counts (workspace is poisoned by the harness)
    for (int i = gi; i < N; i += gsz) cnt[i] = 0;
    grid.sync();
    // B: count
    for (int i = gi; i < E; i += gsz) atomicAdd(&cnt[dst[i]], 1);
    grid.sync();
    // C1: per-256-chunk exclusive scan; chunk sums into bsum
    for (int ch = blockIdx.x; ch < nch; ch += gridDim.x) {
        int i = (ch << 8) + tid;
        int v = (i < N) ? cnt[i] : 0;
        s[tid] = v;
        __syncthreads();
        for (int off = 1; off < 256; off <<= 1) {
            int t = (tid >= off) ? s[tid - off] : 0;
            __syncthreads();
            s[tid] += t;
            __syncthreads();
        }
        if (i < N) rowptr[i] = s[tid] - v;
        if (tid == 255) bsum[ch] = s[tid];
        __syncthreads();
    }
    grid.sync();
    // C2: block 0 exclusive-scans bsum[0..nch)
    if (blockIdx.x == 0) {
        if (tid == 0) carry = 0;
        __syncthreads();
        for (int base = 0; base < nch; base += 256) {
            int idx = base + tid;
            int v = (idx < nch) ? bsum[idx] : 0;
            s[tid] = v;
            __syncthreads();
            for (int off = 1; off < 256; off <<= 1) {
                int t = (tid >= off) ? s[tid - off] : 0;
                __syncthreads();
                s[tid] += t;
                __syncthreads();
            }
            if (idx < nch) bsum[idx] = carry + s[tid] - v;
            __syncthreads();
            if (tid == 0) carry += s[255];
            __syncthreads();
        }
    }
    grid.sync();
    // C3: apply block offsets, init cursor, compute dinv
    for (int i = gi; i < N; i += gsz) {
        int v = rowptr[i] + bsum[i >> 8];
        rowptr[i] = v;
        cursor[i] = v;
        dinv[i] = rsqrtf(1.0f + (float)cnt[i]);
    }
    if (gi == 0) rowptr[N] = E;
    grid.sync();
    // D: scatter edges; pack src index + precomputed coef
    for (int i = gi; i < E; i += gsz) {
        int s0 = src[i], d = dst[i];
        int p = atomicAdd(&cursor[d], 1);
        float c = dinv[s0] * dinv[d];
        ecol[p] = make_int2(s0, __float_as_int(c));
    }
}

// ---------------------------------------------------------------------------
// Layer GEMM, K=128 (4 chunks): hWb = bf16(A @ W). LDS-free; all fragment
// loads issued up front, then MFMAs. A = bf16 slice of xcH (hi only).
// Block 64 rows x 128 cols; wave tile 32x64.
// ---------------------------------------------------------------------------
__global__ __launch_bounds__(256) void k_gemm_lf(
    const u16* __restrict__ A, int colOff,
    const u16* __restrict__ Bt, u16* __restrict__ OUTb, int N)
{
    const int tid  = threadIdx.x;
    const int lane = tid & 63;
    const int wave = tid >> 6;
    const int wr   = wave & 1;
    const int wc   = wave >> 1;
    const int quad = lane >> 4;
    const int l15  = lane & 15;
    const int row0 = blockIdx.x * 64;

    const u16* pA[2];
    #pragma unroll
    for (int i = 0; i < 2; ++i) {
        int r = row0 + wr * 32 + i * 16 + l15;
        if (r >= N) r = N - 1;
        pA[i] = A + (size_t)r * 512 + colOff + quad * 8;
    }
    const u16* pB = Bt + ((size_t)quad * 128 + wc * 64 + l15) * 8;

    bf16x8 ah[4][2], bh[4][4];
    #pragma unroll
    for (int kc = 0; kc < 4; ++kc) {
        #pragma unroll
        for (int i = 0; i < 2; ++i)
            ah[kc][i] = *(const bf16x8*)(pA[i] + kc * 32);
        #pragma unroll
        for (int j = 0; j < 4; ++j)
            bh[kc][j] = *(const bf16x8*)(pB + (size_t)kc * 4096 + j * 128);
    }

    f32x4 acc[2][4];
    #pragma unroll
    for (int i = 0; i < 2; ++i)
        #pragma unroll
        for (int j = 0; j < 4; ++j)
            #pragma unroll
            for (int r = 0; r < 4; ++r) acc[i][j][r] = 0.f;

    #pragma unroll
    for (int kc = 0; kc < 4; ++kc)
        #pragma unroll
        for (int i = 0; i < 2; ++i)
            #pragma unroll
            for (int j = 0; j < 4; ++j)
                acc[i][j] = __builtin_amdgcn_mfma_f32_16x16x32_bf16(ah[kc][i], bh[kc][j], acc[i][j], 0, 0, 0);

    #pragma unroll
    for (int i = 0; i < 2; ++i)
        #pragma unroll
        for (int j = 0; j < 4; ++j) {
            int col = wc * 64 + j * 16 + l15;
            #pragma unroll
            for (int r = 0; r < 4; ++r) {
                int grow = row0 + wr * 32 + i * 16 + quad * 4 + r;
                if (grow < N)
                    OUTb[(size_t)grow * 128 + col] = f2bf(acc[i][j][r]);
            }
        }
}

// ---------------------------------------------------------------------------
// Fused MLP (K-split): 32-row blocks, 4 waves. Unchanged.
// ---------------------------------------------------------------------------
__global__ __launch_bounds__(256) void k_mlp_fused(
    const u16* __restrict__ xcH,
    const u16* __restrict__ B1t, const float* __restrict__ b1,
    const u16* __restrict__ W2h, const u16* __restrict__ W2l,
    const float* __restrict__ b2, float* __restrict__ out, int N)
{
    __shared__ float sAcc[32 * 132];   // K-split partial sums (padded stride)
    __shared__ u16 sZh[32 * 128];      // [(qq*32 + r)*8 + j], z1 col = qq*8+j
    __shared__ u16 sZl[32 * 128];

    const int tid  = threadIdx.x;
    const int lane = tid & 63;
    const int wave = tid >> 6;
    const int wc   = wave & 1;   // 64-col half
    const int kg   = wave >> 1;  // K-group
    const int quad = lane >> 4;
    const int l15  = lane & 15;
    const int row0 = blockIdx.x * 32;

    const u16* pA[2];
    #pragma unroll
    for (int f = 0; f < 2; ++f) {
        int r = row0 + f * 16 + l15;
        if (r >= N) r = N - 1;
        pA[f] = xcH + (size_t)r * 512 + quad * 8;
    }
    const u16* pB = B1t + ((size_t)quad * 128 + wc * 64 + l15) * 8;

    f32x4 acc[2][4];
    #pragma unroll
    for (int f = 0; f < 2; ++f)
        #pragma unroll
        for (int j = 0; j < 4; ++j)
            #pragma unroll
            for (int r = 0; r < 4; ++r) acc[f][j][r] = 0.f;

    // 3-buffer pipeline over this wave's 8 chunks (global chunk g = kg*8 + t)
    bf16x8 abuf[3][2], bbuf[3][4];
    #define LOADI(t, s)                                                          \
        {                                                                        \
            const int g = kg * 8 + (t);                                          \
            _Pragma("unroll")                                                    \
            for (int f = 0; f < 2; ++f)                                          \
                abuf[s][f] = *(const bf16x8*)(pA[f] + g * 32);                   \
            _Pragma("unroll")                                                    \
            for (int j = 0; j < 4; ++j)                                          \
                bbuf[s][j] = *(const bf16x8*)(pB + (size_t)g * 4096 + j * 128);  \
        }
    LOADI(0, 0)
    LOADI(1, 1)
    #pragma unroll
    for (int t = 0; t < 8; ++t) {
        if (t + 2 < 8) {
            const int s = (t + 2) % 3;
            LOADI(t + 2, s)
        }
        const int u = t % 3;
        #pragma unroll
        for (int f = 0; f < 2; ++f)
            #pragma unroll
            for (int j = 0; j < 4; ++j)
                acc[f][j] = __builtin_amdgcn_mfma_f32_16x16x32_bf16(abuf[u][f], bbuf[u][j], acc[f][j], 0, 0, 0);
    }
    #undef LOADI

    // K-split reduction: kg=1 stores partials; kg=0 adds.
    if (kg == 1) {
        #pragma unroll
        for (int f = 0; f < 2; ++f)
            #pragma unroll
            for (int jt = 0; jt < 4; ++jt) {
                int col = wc * 64 + jt * 16 + l15;
                #pragma unroll
                for (int r = 0; r < 4; ++r) {
                    int row = f * 16 + quad * 4 + r;
                    sAcc[row * 132 + col] = acc[f][jt][r];
                }
            }
    }
    __syncthreads();
    if (kg == 0) {
        #pragma unroll
        for (int jt = 0; jt < 4; ++jt) {
            int col = wc * 64 + jt * 16 + l15;
            float bv = b1[col];
            int qq = col >> 3, jj = col & 7;
            #pragma unroll
            for (int f = 0; f < 2; ++f) {
                #pragma unroll
                for (int rr = 0; rr < 4; ++rr) {
                    int row = f * 16 + quad * 4 + rr;
                    float v = fmaxf(acc[f][jt][rr] + sAcc[row * 132 + col] + bv, 0.f);
                    u16 h = f2bf(v);
                    sZh[(qq * 32 + row) * 8 + jj] = h;
                    sZl[(qq * 32 + row) * 8 + jj] = f2bf(v - bf2f(h));
                }
            }
        }
    }
    __syncthreads();

    // phase 2: MLP2 (128->64) + softmax on waves 0,1 (16 rows each)
    if (kg == 0) {
        f32x4 oacc[4];
        #pragma unroll
        for (int j = 0; j < 4; ++j)
            #pragma unroll
            for (int r = 0; r < 4; ++r) oacc[j][r] = 0.f;

        #pragma unroll
        for (int kc = 0; kc < 4; ++kc) {
            int qq = kc * 4 + quad;
            bf16x8 zh = *(const bf16x8*)&sZh[(qq * 32 + wc * 16 + l15) * 8];
            bf16x8 zl = *(const bf16x8*)&sZl[(qq * 32 + wc * 16 + l15) * 8];
            #pragma unroll
            for (int jt = 0; jt < 4; ++jt) {
                int n = jt * 16 + l15;
                bf16x8 wh = *(const bf16x8*)&W2h[(qq * 64 + n) * 8];
                bf16x8 wl = *(const bf16x8*)&W2l[(qq * 64 + n) * 8];
                oacc[jt] = __builtin_amdgcn_mfma_f32_16x16x32_bf16(zh, wh, oacc[jt], 0, 0, 0);
                oacc[jt] = __builtin_amdgcn_mfma_f32_16x16x32_bf16(zh, wl, oacc[jt], 0, 0, 0);
                oacc[jt] = __builtin_amdgcn_mfma_f32_16x16x32_bf16(zl, wh, oacc[jt], 0, 0, 0);
            }
        }

        #pragma unroll
        for (int jt = 0; jt < 4; ++jt) {
            float bv = b2[jt * 16 + l15];
            #pragma unroll
            for (int r = 0; r < 4; ++r) oacc[jt][r] += bv;
        }
        #pragma unroll
        for (int r = 0; r < 4; ++r) {
            float m = fmaxf(fmaxf(oacc[0][r], oacc[1][r]), fmaxf(oacc[2][r], oacc[3][r]));
            #pragma unroll
            for (int mask = 8; mask; mask >>= 1) m = fmaxf(m, __shfl_xor(m, mask, 64));
            float p0 = __expf(oacc[0][r] - m);
            float p1 = __expf(oacc[1][r] - m);
            float p2 = __expf(oacc[2][r] - m);
            float p3 = __expf(oacc[3][r] - m);
            float s = p0 + p1 + p2 + p3;
            #pragma unroll
            for (int mask = 8; mask; mask >>= 1) s += __shfl_xor(s, mask, 64);
            float inv = 1.0f / s;
            int grow = row0 + wc * 16 + quad * 4 + r;
            if (grow < N) {
                float* o = out + (size_t)grow * CC + l15;
                o[0]  = p0 * inv;
                o[16] = p1 * inv;
                o[32] = p2 * inv;
                o[48] = p3 * inv;
            }
        }
    }
}

// ---------------------------------------------------------------------------
// Aggregation (symmetric-normalized, self-loop) + bias + LayerNorm + ReLU.
// Pair-edge layout: each lane owns 4 cols (uint2 = 8B gathers, 32 lanes/row);
// the two 32-lane halves process even/odd edges concurrently, combined at the
// end with one __shfl_xor(...,32). Self-loop term added by half 0 ONLY
// (round-1 bug: both halves added it -> double count after combine).
// ---------------------------------------------------------------------------
__global__ __launch_bounds__(256, 8) void k_agg_ln(
    const u16* __restrict__ hWb,
    const int* __restrict__ rowptr, const int2* __restrict__ ecol,
    const float* __restrict__ dinv,
    const float* __restrict__ bg, const float* __restrict__ g,
    const float* __restrict__ b,
    u16* __restrict__ outHi, int N)
{
    const int lane = threadIdx.x & 63;
    const int h    = lane >> 5;         // half-wave: even/odd edges
    const int c0   = (lane & 31) << 2;  // 4 owned columns

    const float4 bgv = *(const float4*)(bg + c0);
    const float4 gv  = *(const float4*)(g + c0);
    const float4 bv  = *(const float4*)(b + c0);

    const int nwaves = gridDim.x * 4;
    for (int wid = blockIdx.x * 4 + (threadIdx.x >> 6); wid < N; wid += nwaves) {
        float di = dinv[wid];
        float sc = (h == 0) ? di * di : 0.f;   // self-loop: half 0 only!

        // self-loop term (zeroed on half 1; halves are summed below)
        uint2 hv = *(const uint2*)(hWb + (size_t)wid * HH + c0);
        float a0 = bf2f((u16)hv.x) * sc;
        float a1 = bf2f((u16)(hv.x >> 16)) * sc;
        float a2 = bf2f((u16)hv.y) * sc;
        float a3 = bf2f((u16)(hv.y >> 16)) * sc;
        float q0 = 0.f, q1 = 0.f, q2 = 0.f, q3 = 0.f;

        int e0 = rowptr[wid];
        int m  = rowptr[wid + 1] - e0;
        int ch = (m - h + 1) >> 1;           // this half's edge count
        const int2* ep = ecol + e0 + h;      // half h takes edges e0+h, +2, ...

        int k = 0;
        for (; k + 4 <= ch; k += 4) {        // 8 edges per wave-iteration
            int2 p[4];
            uint2 v[4];
            #pragma unroll
            for (int t = 0; t < 4; ++t) p[t] = ep[2 * (k + t)];
            #pragma unroll
            for (int t = 0; t < 4; ++t)
                v[t] = *(const uint2*)(hWb + (size_t)p[t].x * HH + c0);
            #pragma unroll
            for (int t = 0; t < 4; ++t) {
                float c = __int_as_float(p[t].y);
                float x0 = bf2f((u16)v[t].x) * c;
                float x1 = bf2f((u16)(v[t].x >> 16)) * c;
                float x2 = bf2f((u16)v[t].y) * c;
                float x3 = bf2f((u16)(v[t].y >> 16)) * c;
                if (t & 1) { q0 += x0; q1 += x1; q2 += x2; q3 += x3; }
                else       { a0 += x0; a1 += x1; a2 += x2; a3 += x3; }
            }
        }
        for (; k < ch; ++k) {
            int2 p = ep[2 * k];
            uint2 v = *(const uint2*)(hWb + (size_t)p.x * HH + c0);
            float c = __int_as_float(p.y);
            a0 += bf2f((u16)v.x) * c;
            a1 += bf2f((u16)(v.x >> 16)) * c;
            a2 += bf2f((u16)v.y) * c;
            a3 += bf2f((u16)(v.y >> 16)) * c;
        }
        a0 += q0; a1 += q1; a2 += q2; a3 += q3;

        // combine halves (lane ^ 32 holds the same 4 columns)
        a0 += __shfl_xor(a0, 32, 64);
        a1 += __shfl_xor(a1, 32, 64);
        a2 += __shfl_xor(a2, 32, 64);
        a3 += __shfl_xor(a3, 32, 64);
        a0 += bgv.x; a1 += bgv.y; a2 += bgv.z; a3 += bgv.w;

        // LayerNorm over 128 cols (each 32-lane half holds the full row)
        float ssum = (a0 + a1) + (a2 + a3);
        #pragma unroll
        for (int off = 16; off; off >>= 1) ssum += __shfl_xor(ssum, off, 64);
        float mu = ssum * (1.0f / 128.0f);
        float d0 = a0 - mu, d1 = a1 - mu, d2 = a2 - mu, d3 = a3 - mu;
        float vsum = (d0 * d0 + d1 * d1) + (d2 * d2 + d3 * d3);
        #pragma unroll
        for (int off = 16; off; off >>= 1) vsum += __shfl_xor(vsum, off, 64);
        float rstd = rsqrtf(vsum * (1.0f / 128.0f) + LN_EPS);

        if (!h) {  // halves are duplicates after combine; one writes
            float o0 = fmaxf(gv.x * d0 * rstd + bv.x, 0.f);
            float o1 = fmaxf(gv.y * d1 * rstd + bv.y, 0.f);
            float o2 = fmaxf(gv.z * d2 * rstd + bv.z, 0.f);
            float o3 = fmaxf(gv.w * d3 * rstd + bv.w, 0.f);
            uint2 o;
            o.x = (u32)f2bf(o0) | ((u32)f2bf(o1) << 16);
            o.y = (u32)f2bf(o2) | ((u32)f2bf(o3) << 16);
            *(uint2*)&outHi[(size_t)wid * 512 + c0] = o;
        }
    }
}

// ---------------------------------------------------------------------------
// Host launcher
// ---------------------------------------------------------------------------
extern "C" void kernel_launch(void* const* d_in, const int* in_sizes, int n_in,
                              void* d_out, int out_size, void* d_ws, size_t ws_size,
                              hipStream_t stream) {
    const float* x   = (const float*)d_in[0];
    const int*   ei  = (const int*)  d_in[1];
    const float* Wg  = (const float*)d_in[2];
    const float* bg  = (const float*)d_in[3];
    const float* lng = (const float*)d_in[4];
    const float* lnb = (const float*)d_in[5];
    const float* W1  = (const float*)d_in[6];
    const float* b1  = (const float*)d_in[7];
    const float* W2  = (const float*)d_in[8];
    const float* b2  = (const float*)d_in[9];
    float* out = (float*)d_out;

    const int N = in_sizes[0] / D;
    const int E = in_sizes[1] / 2;
    const int* srcp = ei;
    const int* dstp = ei + E;

    char* ws = (char*)d_ws;
    size_t off = 0;
    auto alloc = [&](size_t bytes) -> void* {
        void* p = ws + off;
        off += (bytes + 511) & ~(size_t)511;
        return p;
    };
    int*   cnt    = (int*)  alloc((size_t)N * 4);
    int*   rowptr = (int*)  alloc((size_t)(N + 1) * 4);
    int*   cursor = (int*)  alloc((size_t)N * 4);
    int*   bsum   = (int*)  alloc((size_t)((N + 255) / 256 + 1) * 4);
    int2*  ecol   = (int2*) alloc((size_t)E * 8);
    float* dinv   = (float*)alloc((size_t)N * 4);
    u16*   hWb    = (u16*)  alloc((size_t)N * HH * 2);       // layer GEMM bf16 out
    u16*   xcH    = (u16*)  alloc((size_t)N * 512 * 2);      // [x|f1|f2|f3] bf16
    u16*   WgtH   = (u16*)  alloc((size_t)NLAYERS * D * HH * 2);
    u16*   W1tH   = (u16*)  alloc((size_t)(D + NLAYERS * HH) * HH * 2);
    u16*   W2tH   = (u16*)  alloc((size_t)HH * CC * 2);
    u16*   W2tL   = (u16*)  alloc((size_t)HH * CC * 2);

    const int B = 256;

    // fused prep: x->bf16 (x4) + all weight tilings (one launch)
    const int prepTotal = N * (D / 4) + NLAYERS * D * HH
                        + (D + NLAYERS * HH) * HH + HH * CC;
    k_prep<<<(prepTotal + B - 1) / B, B, 0, stream>>>(x, xcH, Wg, WgtH, W1, W1tH,
                                                      W2, W2tH, W2tL, N);

    // cooperative CSR build (zero->count->scan->apply->scatter, one launch)
    {
        int N_ = N, E_ = E;
        void* cargs[] = { (void*)&srcp, (void*)&dstp, (void*)&cnt, (void*)&rowptr,
                          (void*)&bsum, (void*)&cursor, (void*)&dinv, (void*)&ecol,
                          (void*)&N_, (void*)&E_ };
        hipLaunchCooperativeKernel((const void*)k_csr, dim3(1024), dim3(B),
                                   cargs, 0, stream);
    }

    const int gemmBlocks = (N + 63) / 64;
    const int mlpBlocks  = (N + 31) / 32;
    const int aggBlocks  = 2048;   // persistent: 8192 waves, ~6 nodes/wave

    for (int l = 0; l < NLAYERS; ++l) {
        // hWb = bf16(h @ Wg[l])  (bias added after aggregation)
        k_gemm_lf<<<gemmBlocks, B, 0, stream>>>(xcH, l * HH,
                                                WgtH + (size_t)l * D * HH, hWb, N);
        k_agg_ln<<<aggBlocks, B, 0, stream>>>(hWb, rowptr, ecol, dinv,
                                              bg + (size_t)l * HH,
                                              lng + (size_t)l * HH,
                                              lnb + (size_t)l * HH,
                                              xcH + (size_t)(l + 1) * HH, N);
    }

    // out = softmax(relu([x|f1|f2|f3] @ W1 + b1) @ W2 + b2), fused, K-split
    k_mlp_fused<<<mlpBlocks, B, 0, stream>>>(xcH, W1tH, b1,
                                             W2tH, W2tL, b2, out, N);
}

// Round 3
// 321.675 us; speedup vs baseline: 2.4742x; 2.4742x over previous
//
#include <hip/hip_runtime.h>
#include <math.h>

// Problem constants (shapes fixed by the reference)
#define D 128
#define HH 128
#define CC 64
#define NLAYERS 3
#define LN_EPS 1e-5f

typedef __attribute__((ext_vector_type(8))) short bf16x8;
typedef __attribute__((ext_vector_type(4))) float f32x4;
typedef unsigned short u16;
typedef unsigned int u32;

// round-to-nearest-even fp32 -> bf16 bits
__device__ __forceinline__ u16 f2bf(float f) {
    u32 u = __float_as_uint(f);
    u32 r = u + 0x7FFFu + ((u >> 16) & 1u);
    return (u16)(r >> 16);
}
__device__ __forceinline__ float bf2f(u16 h) {
    return __uint_as_float(((u32)h) << 16);
}

// ---------------------------------------------------------------------------
// k_prep: fused setup — zero cnt + x->bf16 (float4-vectorized, into xcH cols
// 0:128) + tile Wg (3 layers) + tile W1 + tile W2 (hi/lo).
// Tiled layout: [kc][q][n][j], k = kc*32 + q*8 + j.
// ---------------------------------------------------------------------------
__global__ void k_prep(const float* __restrict__ x, u16* __restrict__ xh,
                       const float* __restrict__ Wg, u16* __restrict__ WgtH,
                       const float* __restrict__ W1, u16* __restrict__ W1tH,
                       const float* __restrict__ W2, u16* __restrict__ W2tH,
                       u16* __restrict__ W2tL,
                       int* __restrict__ cnt, int N)
{
    int i = blockIdx.x * blockDim.x + threadIdx.x;
    // seg 0: zero cnt (workspace is poisoned by the harness)
    if (i < N) { cnt[i] = 0; return; }
    i -= N;
    // seg 1: x -> bf16 hi, 4 elements per thread (float4 load, ushort4 store)
    int nx4 = N * (D / 4);
    if (i < nx4) {
        float4 v = *(const float4*)(x + (size_t)i * 4);
        int row = i >> 5, c = (i & 31) << 2;
        ushort4 o;
        o.x = f2bf(v.x); o.y = f2bf(v.y); o.z = f2bf(v.z); o.w = f2bf(v.w);
        *(ushort4*)&xh[(size_t)row * 512 + c] = o;
        return;
    }
    i -= nx4;
    // seg 2: Wg (3 stacked 128x128 matrices; layout linear in kc)
    if (i < NLAYERS * D * HH) {
        int k = i >> 7, n = i & 127;
        int kc = k >> 5, q = (k >> 3) & 3, j = k & 7;
        WgtH[(((kc * 4 + q) << 7) + n) * 8 + j] = f2bf(Wg[i]);
        return;
    }
    i -= NLAYERS * D * HH;
    // seg 3: W1 (512x128)
    if (i < (D + NLAYERS * HH) * HH) {
        int k = i >> 7, n = i & 127;
        int kc = k >> 5, q = (k >> 3) & 3, j = k & 7;
        W1tH[(((kc * 4 + q) << 7) + n) * 8 + j] = f2bf(W1[i]);
        return;
    }
    i -= (D + NLAYERS * HH) * HH;
    // seg 4: W2 (128x64), hi + lo (split-3 in mlp phase 2)
    if (i < HH * CC) {
        int k = i >> 6, n = i & 63;
        int kc = k >> 5, q = (k >> 3) & 3, j = k & 7;
        float v = W2[i];
        u16 h = f2bf(v);
        int o = (((kc * 4 + q) << 6) + n) * 8 + j;
        W2tH[o] = h;
        W2tL[o] = f2bf(v - bf2f(h));
    }
}

// ---------------------------------------------------------------------------
// CSR build: count -> scan_a -> scan_c (block-sum scan inlined) -> scatter.
// Separate small launches: grid.sync() on MI355X costs ~100 µs/barrier
// (round-2 measurement: fused cooperative version = 527 µs vs ~50 µs here).
// ---------------------------------------------------------------------------

__global__ void k_count(const int* __restrict__ dst, int* __restrict__ cnt, int E) {
    int i = blockIdx.x * blockDim.x + threadIdx.x;
    if (i < E) atomicAdd(&cnt[dst[i]], 1);
}

__global__ void k_scan_a(const int* __restrict__ cnt, int* __restrict__ rowptr,
                         int* __restrict__ bsum, int N) {
    __shared__ int s[1024];
    int tid = threadIdx.x;
    int i = blockIdx.x * 1024 + tid;
    int v = (i < N) ? cnt[i] : 0;
    s[tid] = v;
    __syncthreads();
    for (int off = 1; off < 1024; off <<= 1) {
        int t = (tid >= off) ? s[tid - off] : 0;
        __syncthreads();
        s[tid] += t;
        __syncthreads();
    }
    if (i < N) rowptr[i] = s[tid] - v;
    if (tid == 1023) bsum[blockIdx.x] = s[tid];
}

// finalize: each block re-scans the <=64 block sums (first wave), then applies;
// also computes dinv.
__global__ void k_scan_c(int* __restrict__ rowptr, const int* __restrict__ bsum,
                         const int* __restrict__ cnt, float* __restrict__ dinv,
                         int* __restrict__ cursor, int N, int E, int nsb) {
    __shared__ int sb[64];
    if (threadIdx.x < 64) {
        int t = threadIdx.x;
        int v = (t < nsb) ? bsum[t] : 0;
        int incl = v;
        #pragma unroll
        for (int off = 1; off < 64; off <<= 1) {
            int u = __shfl_up(incl, off, 64);
            if (t >= off) incl += u;
        }
        sb[t] = incl - v;   // exclusive
    }
    __syncthreads();
    int i = blockIdx.x * blockDim.x + threadIdx.x;
    if (i < N) {
        int v = rowptr[i] + sb[i >> 10];
        rowptr[i] = v;
        cursor[i] = v;
        dinv[i] = rsqrtf(1.0f + (float)cnt[i]);
    }
    if (i == 0) rowptr[N] = E;
}

// Scatter edges into CSR; pack src index + precomputed coef (dinv_s * dinv_d)
__global__ void k_scatter(const int* __restrict__ src, const int* __restrict__ dst,
                          const float* __restrict__ dinv,
                          int* __restrict__ cursor, int2* __restrict__ ecol, int E) {
    int i = blockIdx.x * blockDim.x + threadIdx.x;
    if (i < E) {
        int s = src[i], d = dst[i];
        int p = atomicAdd(&cursor[d], 1);
        float c = dinv[s] * dinv[d];
        ecol[p] = make_int2(s, __float_as_int(c));
    }
}

// ---------------------------------------------------------------------------
// Layer GEMM, K=128 (4 chunks): hWb = bf16(A @ W). LDS-free; all fragment
// loads issued up front, then MFMAs. A = bf16 slice of xcH (hi only).
// Block 64 rows x 128 cols; wave tile 32x64.
// ---------------------------------------------------------------------------
__global__ __launch_bounds__(256) void k_gemm_lf(
    const u16* __restrict__ A, int colOff,
    const u16* __restrict__ Bt, u16* __restrict__ OUTb, int N)
{
    const int tid  = threadIdx.x;
    const int lane = tid & 63;
    const int wave = tid >> 6;
    const int wr   = wave & 1;
    const int wc   = wave >> 1;
    const int quad = lane >> 4;
    const int l15  = lane & 15;
    const int row0 = blockIdx.x * 64;

    const u16* pA[2];
    #pragma unroll
    for (int i = 0; i < 2; ++i) {
        int r = row0 + wr * 32 + i * 16 + l15;
        if (r >= N) r = N - 1;
        pA[i] = A + (size_t)r * 512 + colOff + quad * 8;
    }
    const u16* pB = Bt + ((size_t)quad * 128 + wc * 64 + l15) * 8;

    bf16x8 ah[4][2], bh[4][4];
    #pragma unroll
    for (int kc = 0; kc < 4; ++kc) {
        #pragma unroll
        for (int i = 0; i < 2; ++i)
            ah[kc][i] = *(const bf16x8*)(pA[i] + kc * 32);
        #pragma unroll
        for (int j = 0; j < 4; ++j)
            bh[kc][j] = *(const bf16x8*)(pB + (size_t)kc * 4096 + j * 128);
    }

    f32x4 acc[2][4];
    #pragma unroll
    for (int i = 0; i < 2; ++i)
        #pragma unroll
        for (int j = 0; j < 4; ++j)
            #pragma unroll
            for (int r = 0; r < 4; ++r) acc[i][j][r] = 0.f;

    #pragma unroll
    for (int kc = 0; kc < 4; ++kc)
        #pragma unroll
        for (int i = 0; i < 2; ++i)
            #pragma unroll
            for (int j = 0; j < 4; ++j)
                acc[i][j] = __builtin_amdgcn_mfma_f32_16x16x32_bf16(ah[kc][i], bh[kc][j], acc[i][j], 0, 0, 0);

    #pragma unroll
    for (int i = 0; i < 2; ++i)
        #pragma unroll
        for (int j = 0; j < 4; ++j) {
            int col = wc * 64 + j * 16 + l15;
            #pragma unroll
            for (int r = 0; r < 4; ++r) {
                int grow = row0 + wr * 32 + i * 16 + quad * 4 + r;
                if (grow < N)
                    OUTb[(size_t)grow * 128 + col] = f2bf(acc[i][j][r]);
            }
        }
}

// ---------------------------------------------------------------------------
// Fused MLP (K-split): 32-row blocks, 4 waves.
// ---------------------------------------------------------------------------
__global__ __launch_bounds__(256) void k_mlp_fused(
    const u16* __restrict__ xcH,
    const u16* __restrict__ B1t, const float* __restrict__ b1,
    const u16* __restrict__ W2h, const u16* __restrict__ W2l,
    const float* __restrict__ b2, float* __restrict__ out, int N)
{
    __shared__ float sAcc[32 * 132];   // K-split partial sums (padded stride)
    __shared__ u16 sZh[32 * 128];      // [(qq*32 + r)*8 + j], z1 col = qq*8+j
    __shared__ u16 sZl[32 * 128];

    const int tid  = threadIdx.x;
    const int lane = tid & 63;
    const int wave = tid >> 6;
    const int wc   = wave & 1;   // 64-col half
    const int kg   = wave >> 1;  // K-group
    const int quad = lane >> 4;
    const int l15  = lane & 15;
    const int row0 = blockIdx.x * 32;

    const u16* pA[2];
    #pragma unroll
    for (int f = 0; f < 2; ++f) {
        int r = row0 + f * 16 + l15;
        if (r >= N) r = N - 1;
        pA[f] = xcH + (size_t)r * 512 + quad * 8;
    }
    const u16* pB = B1t + ((size_t)quad * 128 + wc * 64 + l15) * 8;

    f32x4 acc[2][4];
    #pragma unroll
    for (int f = 0; f < 2; ++f)
        #pragma unroll
        for (int j = 0; j < 4; ++j)
            #pragma unroll
            for (int r = 0; r < 4; ++r) acc[f][j][r] = 0.f;

    // 3-buffer pipeline over this wave's 8 chunks (global chunk g = kg*8 + t)
    bf16x8 abuf[3][2], bbuf[3][4];
    #define LOADI(t, s)                                                          \
        {                                                                        \
            const int g = kg * 8 + (t);                                          \
            _Pragma("unroll")                                                    \
            for (int f = 0; f < 2; ++f)                                          \
                abuf[s][f] = *(const bf16x8*)(pA[f] + g * 32);                   \
            _Pragma("unroll")                                                    \
            for (int j = 0; j < 4; ++j)                                          \
                bbuf[s][j] = *(const bf16x8*)(pB + (size_t)g * 4096 + j * 128);  \
        }
    LOADI(0, 0)
    LOADI(1, 1)
    #pragma unroll
    for (int t = 0; t < 8; ++t) {
        if (t + 2 < 8) {
            const int s = (t + 2) % 3;
            LOADI(t + 2, s)
        }
        const int u = t % 3;
        #pragma unroll
        for (int f = 0; f < 2; ++f)
            #pragma unroll
            for (int j = 0; j < 4; ++j)
                acc[f][j] = __builtin_amdgcn_mfma_f32_16x16x32_bf16(abuf[u][f], bbuf[u][j], acc[f][j], 0, 0, 0);
    }
    #undef LOADI

    // K-split reduction: kg=1 stores partials; kg=0 adds.
    if (kg == 1) {
        #pragma unroll
        for (int f = 0; f < 2; ++f)
            #pragma unroll
            for (int jt = 0; jt < 4; ++jt) {
                int col = wc * 64 + jt * 16 + l15;
                #pragma unroll
                for (int r = 0; r < 4; ++r) {
                    int row = f * 16 + quad * 4 + r;
                    sAcc[row * 132 + col] = acc[f][jt][r];
                }
            }
    }
    __syncthreads();
    if (kg == 0) {
        #pragma unroll
        for (int jt = 0; jt < 4; ++jt) {
            int col = wc * 64 + jt * 16 + l15;
            float bv = b1[col];
            int qq = col >> 3, jj = col & 7;
            #pragma unroll
            for (int f = 0; f < 2; ++f) {
                #pragma unroll
                for (int rr = 0; rr < 4; ++rr) {
                    int row = f * 16 + quad * 4 + rr;
                    float v = fmaxf(acc[f][jt][rr] + sAcc[row * 132 + col] + bv, 0.f);
                    u16 h = f2bf(v);
                    sZh[(qq * 32 + row) * 8 + jj] = h;
                    sZl[(qq * 32 + row) * 8 + jj] = f2bf(v - bf2f(h));
                }
            }
        }
    }
    __syncthreads();

    // phase 2: MLP2 (128->64) + softmax on waves 0,1 (16 rows each)
    if (kg == 0) {
        f32x4 oacc[4];
        #pragma unroll
        for (int j = 0; j < 4; ++j)
            #pragma unroll
            for (int r = 0; r < 4; ++r) oacc[j][r] = 0.f;

        #pragma unroll
        for (int kc = 0; kc < 4; ++kc) {
            int qq = kc * 4 + quad;
            bf16x8 zh = *(const bf16x8*)&sZh[(qq * 32 + wc * 16 + l15) * 8];
            bf16x8 zl = *(const bf16x8*)&sZl[(qq * 32 + wc * 16 + l15) * 8];
            #pragma unroll
            for (int jt = 0; jt < 4; ++jt) {
                int n = jt * 16 + l15;
                bf16x8 wh = *(const bf16x8*)&W2h[(qq * 64 + n) * 8];
                bf16x8 wl = *(const bf16x8*)&W2l[(qq * 64 + n) * 8];
                oacc[jt] = __builtin_amdgcn_mfma_f32_16x16x32_bf16(zh, wh, oacc[jt], 0, 0, 0);
                oacc[jt] = __builtin_amdgcn_mfma_f32_16x16x32_bf16(zh, wl, oacc[jt], 0, 0, 0);
                oacc[jt] = __builtin_amdgcn_mfma_f32_16x16x32_bf16(zl, wh, oacc[jt], 0, 0, 0);
            }
        }

        #pragma unroll
        for (int jt = 0; jt < 4; ++jt) {
            float bv = b2[jt * 16 + l15];
            #pragma unroll
            for (int r = 0; r < 4; ++r) oacc[jt][r] += bv;
        }
        #pragma unroll
        for (int r = 0; r < 4; ++r) {
            float m = fmaxf(fmaxf(oacc[0][r], oacc[1][r]), fmaxf(oacc[2][r], oacc[3][r]));
            #pragma unroll
            for (int mask = 8; mask; mask >>= 1) m = fmaxf(m, __shfl_xor(m, mask, 64));
            float p0 = __expf(oacc[0][r] - m);
            float p1 = __expf(oacc[1][r] - m);
            float p2 = __expf(oacc[2][r] - m);
            float p3 = __expf(oacc[3][r] - m);
            float s = p0 + p1 + p2 + p3;
            #pragma unroll
            for (int mask = 8; mask; mask >>= 1) s += __shfl_xor(s, mask, 64);
            float inv = 1.0f / s;
            int grow = row0 + wc * 16 + quad * 4 + r;
            if (grow < N) {
                float* o = out + (size_t)grow * CC + l15;
                o[0]  = p0 * inv;
                o[16] = p1 * inv;
                o[32] = p2 * inv;
                o[48] = p3 * inv;
            }
        }
    }
}

// ---------------------------------------------------------------------------
// Aggregation (symmetric-normalized, self-loop) + bias + LayerNorm + ReLU.
// Pair-edge layout: each lane owns 4 cols (uint2 = 8B gathers, 32 lanes/row);
// the two 32-lane halves process even/odd edges concurrently, combined at the
// end with one __shfl_xor(...,32). Self-loop term added by half 0 ONLY.
// ---------------------------------------------------------------------------
__global__ __launch_bounds__(256, 8) void k_agg_ln(
    const u16* __restrict__ hWb,
    const int* __restrict__ rowptr, const int2* __restrict__ ecol,
    const float* __restrict__ dinv,
    const float* __restrict__ bg, const float* __restrict__ g,
    const float* __restrict__ b,
    u16* __restrict__ outHi, int N)
{
    const int lane = threadIdx.x & 63;
    const int h    = lane >> 5;         // half-wave: even/odd edges
    const int c0   = (lane & 31) << 2;  // 4 owned columns

    const float4 bgv = *(const float4*)(bg + c0);
    const float4 gv  = *(const float4*)(g + c0);
    const float4 bv  = *(const float4*)(b + c0);

    const int nwaves = gridDim.x * 4;
    for (int wid = blockIdx.x * 4 + (threadIdx.x >> 6); wid < N; wid += nwaves) {
        float di = dinv[wid];
        float sc = (h == 0) ? di * di : 0.f;   // self-loop: half 0 only

        uint2 hv = *(const uint2*)(hWb + (size_t)wid * HH + c0);
        float a0 = bf2f((u16)hv.x) * sc;
        float a1 = bf2f((u16)(hv.x >> 16)) * sc;
        float a2 = bf2f((u16)hv.y) * sc;
        float a3 = bf2f((u16)(hv.y >> 16)) * sc;
        float q0 = 0.f, q1 = 0.f, q2 = 0.f, q3 = 0.f;

        int e0 = rowptr[wid];
        int m  = rowptr[wid + 1] - e0;
        int ch = (m - h + 1) >> 1;           // this half's edge count
        const int2* ep = ecol + e0 + h;      // half h takes edges e0+h, +2, ...

        int k = 0;
        for (; k + 4 <= ch; k += 4) {        // 8 edges per wave-iteration
            int2 p[4];
            uint2 v[4];
            #pragma unroll
            for (int t = 0; t < 4; ++t) p[t] = ep[2 * (k + t)];
            #pragma unroll
            for (int t = 0; t < 4; ++t)
                v[t] = *(const uint2*)(hWb + (size_t)p[t].x * HH + c0);
            #pragma unroll
            for (int t = 0; t < 4; ++t) {
                float c = __int_as_float(p[t].y);
                float x0 = bf2f((u16)v[t].x) * c;
                float x1 = bf2f((u16)(v[t].x >> 16)) * c;
                float x2 = bf2f((u16)v[t].y) * c;
                float x3 = bf2f((u16)(v[t].y >> 16)) * c;
                if (t & 1) { q0 += x0; q1 += x1; q2 += x2; q3 += x3; }
                else       { a0 += x0; a1 += x1; a2 += x2; a3 += x3; }
            }
        }
        for (; k < ch; ++k) {
            int2 p = ep[2 * k];
            uint2 v = *(const uint2*)(hWb + (size_t)p.x * HH + c0);
            float c = __int_as_float(p.y);
            a0 += bf2f((u16)v.x) * c;
            a1 += bf2f((u16)(v.x >> 16)) * c;
            a2 += bf2f((u16)v.y) * c;
            a3 += bf2f((u16)(v.y >> 16)) * c;
        }
        a0 += q0; a1 += q1; a2 += q2; a3 += q3;

        // combine halves (lane ^ 32 holds the same 4 columns)
        a0 += __shfl_xor(a0, 32, 64);
        a1 += __shfl_xor(a1, 32, 64);
        a2 += __shfl_xor(a2, 32, 64);
        a3 += __shfl_xor(a3, 32, 64);
        a0 += bgv.x; a1 += bgv.y; a2 += bgv.z; a3 += bgv.w;

        // LayerNorm over 128 cols (each 32-lane half holds the full row)
        float ssum = (a0 + a1) + (a2 + a3);
        #pragma unroll
        for (int off = 16; off; off >>= 1) ssum += __shfl_xor(ssum, off, 64);
        float mu = ssum * (1.0f / 128.0f);
        float d0 = a0 - mu, d1 = a1 - mu, d2 = a2 - mu, d3 = a3 - mu;
        float vsum = (d0 * d0 + d1 * d1) + (d2 * d2 + d3 * d3);
        #pragma unroll
        for (int off = 16; off; off >>= 1) vsum += __shfl_xor(vsum, off, 64);
        float rstd = rsqrtf(vsum * (1.0f / 128.0f) + LN_EPS);

        if (!h) {  // halves are duplicates after combine; one writes
            float o0 = fmaxf(gv.x * d0 * rstd + bv.x, 0.f);
            float o1 = fmaxf(gv.y * d1 * rstd + bv.y, 0.f);
            float o2 = fmaxf(gv.z * d2 * rstd + bv.z, 0.f);
            float o3 = fmaxf(gv.w * d3 * rstd + bv.w, 0.f);
            uint2 o;
            o.x = (u32)f2bf(o0) | ((u32)f2bf(o1) << 16);
            o.y = (u32)f2bf(o2) | ((u32)f2bf(o3) << 16);
            *(uint2*)&outHi[(size_t)wid * 512 + c0] = o;
        }
    }
}

// ---------------------------------------------------------------------------
// Host launcher
// ---------------------------------------------------------------------------
extern "C" void kernel_launch(void* const* d_in, const int* in_sizes, int n_in,
                              void* d_out, int out_size, void* d_ws, size_t ws_size,
                              hipStream_t stream) {
    const float* x   = (const float*)d_in[0];
    const int*   ei  = (const int*)  d_in[1];
    const float* Wg  = (const float*)d_in[2];
    const float* bg  = (const float*)d_in[3];
    const float* lng = (const float*)d_in[4];
    const float* lnb = (const float*)d_in[5];
    const float* W1  = (const float*)d_in[6];
    const float* b1  = (const float*)d_in[7];
    const float* W2  = (const float*)d_in[8];
    const float* b2  = (const float*)d_in[9];
    float* out = (float*)d_out;

    const int N = in_sizes[0] / D;
    const int E = in_sizes[1] / 2;
    const int* srcp = ei;
    const int* dstp = ei + E;

    char* ws = (char*)d_ws;
    size_t off = 0;
    auto alloc = [&](size_t bytes) -> void* {
        void* p = ws + off;
        off += (bytes + 511) & ~(size_t)511;
        return p;
    };
    int*   cnt    = (int*)  alloc((size_t)N * 4);
    int*   rowptr = (int*)  alloc((size_t)(N + 1) * 4);
    int*   cursor = (int*)  alloc((size_t)N * 4);
    int*   bsum   = (int*)  alloc(64 * 4);
    int2*  ecol   = (int2*) alloc((size_t)E * 8);
    float* dinv   = (float*)alloc((size_t)N * 4);
    u16*   hWb    = (u16*)  alloc((size_t)N * HH * 2);       // layer GEMM bf16 out
    u16*   xcH    = (u16*)  alloc((size_t)N * 512 * 2);      // [x|f1|f2|f3] bf16
    u16*   WgtH   = (u16*)  alloc((size_t)NLAYERS * D * HH * 2);
    u16*   W1tH   = (u16*)  alloc((size_t)(D + NLAYERS * HH) * HH * 2);
    u16*   W2tH   = (u16*)  alloc((size_t)HH * CC * 2);
    u16*   W2tL   = (u16*)  alloc((size_t)HH * CC * 2);

    const int B = 256;
    const int gE = (E + B - 1) / B;
    const int nsb = (N + 1023) / 1024;

    // fused prep: zero cnt + x->bf16 (x4) + all weight tilings (one launch)
    const int prepTotal = N + N * (D / 4) + NLAYERS * D * HH
                        + (D + NLAYERS * HH) * HH + HH * CC;
    k_prep<<<(prepTotal + B - 1) / B, B, 0, stream>>>(x, xcH, Wg, WgtH, W1, W1tH,
                                                      W2, W2tH, W2tL, cnt, N);
    k_count<<<gE, B, 0, stream>>>(dstp, cnt, E);
    k_scan_a<<<nsb, 1024, 0, stream>>>(cnt, rowptr, bsum, N);
    k_scan_c<<<(N + B - 1) / B, B, 0, stream>>>(rowptr, bsum, cnt, dinv, cursor, N, E, nsb);
    k_scatter<<<gE, B, 0, stream>>>(srcp, dstp, dinv, cursor, ecol, E);

    const int gemmBlocks = (N + 63) / 64;
    const int mlpBlocks  = (N + 31) / 32;
    const int aggBlocks  = 2048;   // persistent: 8192 waves, ~6 nodes/wave

    for (int l = 0; l < NLAYERS; ++l) {
        // hWb = bf16(h @ Wg[l])  (bias added after aggregation)
        k_gemm_lf<<<gemmBlocks, B, 0, stream>>>(xcH, l * HH,
                                                WgtH + (size_t)l * D * HH, hWb, N);
        k_agg_ln<<<aggBlocks, B, 0, stream>>>(hWb, rowptr, ecol, dinv,
                                              bg + (size_t)l * HH,
                                              lng + (size_t)l * HH,
                                              lnb + (size_t)l * HH,
                                              xcH + (size_t)(l + 1) * HH, N);
    }

    // out = softmax(relu([x|f1|f2|f3] @ W1 + b1) @ W2 + b2), fused, K-split
    k_mlp_fused<<<mlpBlocks, B, 0, stream>>>(xcH, W1tH, b1,
                                             W2tH, W2tL, b2, out, N);
}